// Round 1
// 646.388 us; speedup vs baseline: 1.0470x; 1.0470x over previous
//
#include <hip/hip_runtime.h>

// Problem constants: x[B,C,H,W] fp32, perm[B,G*G] int32, G=4.
constexpr int B = 16, C = 128, H = 224, W = 224, G = 4;
constexpr int BH = H / G;          // 56 rows per block
constexpr int BW4 = (W / G) / 4;   // 14 float4 per block segment
constexpr int W4 = W / 4;          // 56 float4 per image row (896 B = 7 x 128B lines)
constexpr int CCHUNK = 8;          // channels per workgroup
constexpr int QROW = G * W4;       // 224 float4: one (b,c,y) quad-row (si=0..3)
constexpr int NF4 = CCHUNK * QROW; // 1792 float4 staged per workgroup (28 KiB)
constexpr int THREADS = 256;
constexpr int PER_THREAD = NF4 / THREADS; // 7
constexpr int NWG = B * BH * (C / CCHUNK); // 16*56*16 = 14336 workgroups

// The permutation moves 224B blocks only among the 4 rows {si*56+y} of a fixed
// (b, y). Stage those 4 full rows x 8 channels in LDS, permute, write 4 full
// output rows. Both global phases are whole-row (896B, 128B-aligned) accesses:
// fetch == write == compulsory 411 MB, no partial-line RMW across XCDs.
__global__ __launch_bounds__(256) void block_shuffle_lds(
    const float4* __restrict__ x, const int* __restrict__ perm,
    float4* __restrict__ out) {
  __shared__ float4 tile[NF4];
  __shared__ int inv[G * G];

  int wg = blockIdx.x;
  int cblk = wg % (C / CCHUNK);  // 16 channel chunks
  int t    = wg / (C / CCHUNK);
  int y    = t % BH;             // row-within-block [0,56)
  int b    = t / BH;             // batch
  int c0   = cblk * CCHUNK;

  int tid = threadIdx.x;
  // Invert this batch's permutation: out block p=perm[k] sources block k.
  if (tid < G * G) {
    int p = perm[b * (G * G) + tid];
    inv[p] = tid;
  }

  int basebc = (b * C + c0) * H;  // fits in int: max index 25.7M

  // Stage: 8 channels x 4 input rows (si*BH + y), each row 56 contiguous float4.
#pragma unroll
  for (int p = 0; p < PER_THREAD; ++p) {
    int j  = tid + p * THREADS;
    int cc = j / QROW;
    int w  = j - cc * QROW;      // si*56 + w4
    int si = w / W4;
    int w4 = w - si * W4;
    tile[j] = x[(basebc + cc * H + si * BH + y) * W4 + w4];
  }
  __syncthreads();

  // Drain: 8 channels x 4 output rows (oi*BH + y), gathering permuted 224B
  // segments from LDS; global writes are whole contiguous rows.
#pragma unroll
  for (int p = 0; p < PER_THREAD; ++p) {
    int j   = tid + p * THREADS;
    int cc  = j / QROW;
    int w   = j - cc * QROW;     // oi*56 + w4
    int oi  = w / W4;
    int w4  = w - oi * W4;
    int oj  = w4 / BW4;
    int x4  = w4 - oj * BW4;
    int src = inv[oi * G + oj];
    int si  = src >> 2;
    int sj  = src & 3;
    float4 v = tile[cc * QROW + si * W4 + sj * BW4 + x4];
    out[(basebc + cc * H + oi * BH + y) * W4 + w4] = v;
  }
}

extern "C" void kernel_launch(void* const* d_in, const int* in_sizes, int n_in,
                              void* d_out, int out_size, void* d_ws, size_t ws_size,
                              hipStream_t stream) {
  const float4* x = (const float4*)d_in[0];
  const int* perm = (const int*)d_in[1];
  float4* out = (float4*)d_out;
  block_shuffle_lds<<<NWG, THREADS, 0, stream>>>(x, perm, out);
}